// Round 5
// baseline (218.339 us; speedup 1.0000x reference)
//
#include <hip/hip_runtime.h>
#include <hip/hip_cooperative_groups.h>

#define NN 512
#define NE 16384
#define NF 64

namespace cg = cooperative_groups;

typedef __attribute__((ext_vector_type(8))) short short8_t;
typedef __attribute__((ext_vector_type(4))) float float4_t;

__device__ inline unsigned short f2bf(float f) {
  unsigned u = __builtin_bit_cast(unsigned, f);
  u += 0x7fff + ((u >> 16) & 1);  // round-to-nearest-even (finite inputs)
  return (unsigned short)(u >> 16);
}
__device__ inline float bf2f(unsigned short u) {
  unsigned v = ((unsigned)u) << 16;
  return __builtin_bit_cast(float, v);
}

// ---------------------------------------------------------------------------
// MEGA kernel (cooperative, grid 256 x 512, 1 block/CU, ~110 KB LDS):
//   Phase 1 (pre grid.sync):
//     threads   0-255 : k1 = X=C@W1^T, Y=C@W2^T (bf16 MFMA) + eid scatter
//     threads 256-351 : W_mlp1/W_mlp2 fp32->bf16 conversion (96 granules/blk)
//     block 0 t>=384  : build maskO in LDS (atomicOr) -> coalesced global store
//     block 1 t>=384  : build maskI likewise
//     (global memset of masks eliminated entirely)
//     phase-2 C rows + ei loads hoisted to kernel top (latency hidden here)
//   grid.sync  (device-scope fence: eid/Xb/Yb/masks/W1B/W2B handoff)
//   Phase 2 = R4's k_spmlp verbatim (spmm via mask intersection -> TM in LDS
//     -> 2-layer MLP with 4-chunk weight staging), mask reads post-sync.
// Numerics identical to R4 (same fma order, same bf16 rounding).
// ---------------------------------------------------------------------------
#define STAGE(it) { \
    uint4* d1 = (uint4*)W1s; const uint4* s1g = (const uint4*)W1B; \
    _Pragma("unroll") for (int z = 0; z < 4; z++) { \
      int gi = z * 512 + t; int r = gi >> 4, c = gi & 15; \
      int grow = ((r >> 6) * 4 + (it)) * 64 + (r & 63); \
      d1[r * 17 + c] = s1g[(size_t)grow * 16 + c]; } \
    uint4* d2 = (uint4*)W2s; const uint4* s2g = (const uint4*)W2B; \
    _Pragma("unroll") for (int z = 0; z < 2; z++) { \
      int gi = z * 512 + t; int r = gi >> 4, c = gi & 15; \
      int gc = ((c >> 3) * 4 + (it)) * 8 + (c & 7); \
      d2[r * 17 + c] = s2g[(size_t)r * 64 + gc]; } }

#define REMBATCH(le, ii, kk, cnt, ac) { \
    int t2 = base + b; \
    int jj = jlbase[(le) * 32 + (t2 < (cnt) ? t2 : base)] & 511; \
    int sv = eid[(gl < 8) ? ((ii) * NN + jj) : (jj * NN + (kk))]; \
    short4 xs[8], ys[8]; \
    _Pragma("unroll") for (int b2 = 0; b2 < 8; b2++) { \
      int s1 = __shfl(sv, (lane & 48) | b2); \
      int s2 = __shfl(sv, (lane & 48) | (8 + b2)); \
      xs[b2] = *(const short4*)(Xb + (size_t)s1 * 64 + gl * 4); \
      ys[b2] = *(const short4*)(Yb + (size_t)s2 * 64 + gl * 4); } \
    _Pragma("unroll") for (int b2 = 0; b2 < 8; b2++) if (base + b2 < (cnt)) { \
      ac[0] = fmaf(bf2f((unsigned short)xs[b2].x), bf2f((unsigned short)ys[b2].x), ac[0]); \
      ac[1] = fmaf(bf2f((unsigned short)xs[b2].y), bf2f((unsigned short)ys[b2].y), ac[1]); \
      ac[2] = fmaf(bf2f((unsigned short)xs[b2].z), bf2f((unsigned short)ys[b2].z), ac[2]); \
      ac[3] = fmaf(bf2f((unsigned short)xs[b2].w), bf2f((unsigned short)ys[b2].w), ac[3]); } }

__global__ __launch_bounds__(512) void k_mega(
    const int* __restrict__ ei,
    const float* __restrict__ C,
    const float* __restrict__ W1,
    const float* __restrict__ W2,
    const float* __restrict__ Wm1,
    const float* __restrict__ Wm2,
    int* __restrict__ eid,
    unsigned* __restrict__ maskO,
    unsigned* __restrict__ maskI,
    unsigned short* __restrict__ Xb,
    unsigned short* __restrict__ Yb,
    unsigned short* __restrict__ W1B,
    unsigned short* __restrict__ W2B,
    float* __restrict__ out) {
  __shared__ __attribute__((aligned(16))) short W1s[128 * 136];  // 34816 B
  __shared__ __attribute__((aligned(16))) short W2s[64 * 136];   // 17408 B
  __shared__ __attribute__((aligned(16))) short hS[8][16 * 72];  // 18432 B (k1W overlay / jl overlay / hS)
  __shared__ __attribute__((aligned(16))) short tm[64 * 72];     //  9216 B
  __shared__ unsigned mlds[8192];                                // 32768 B (builder blocks)
  // total 112640 B -> 1 block/CU; grid 256 == #CUs (cooperative co-resident)

  int t = threadIdx.x;
  int w = t >> 6;
  int lane = t & 63;
  int gl = lane & 15;   // lane-in-group (phase S)
  int grp = lane >> 4;  // group-in-wave (phase S)
  unsigned short* jlbase = (unsigned short*)hS;  // [64][32], phase-S only
  short* k1W1s = &hS[0][0];                      // 9216 B, phase-1 only
  short* k1W2s = k1W1s + 64 * 72;                // 9216 B, phase-1 only

  // ----- phase-M indices -----
  int u = w >> 2;
  int wl = w & 3;
  int g = wl & 1;
  int h = wl >> 1;
  int col = lane & 15;
  int q = lane >> 4;
  int base_e = blockIdx.x * 64 + u * 32 + g * 16;
  int lem = u * 32 + g * 16 + col;

  // ----- phase-S edge ids (hoisted; inputs only) -----
  int le0 = w * 4 + grp;
  int le1 = 32 + w * 4 + grp;
  int e0 = blockIdx.x * 64 + le0;
  int e1 = blockIdx.x * 64 + le1;
  int i0 = ei[e0], k0 = ei[NE + e0];
  int i1 = ei[e1], k1 = ei[NE + e1];

  // ----- hoisted phase-M C rows (fp32; latency hidden under phase 1) -----
  float4 craw[4];
#pragma unroll
  for (int ks = 0; ks < 2; ks++) {
    craw[2 * ks]     = ((const float4*)C)[(size_t)(base_e + col) * 16 + ks * 8 + q * 2];
    craw[2 * ks + 1] = ((const float4*)C)[(size_t)(base_e + col) * 16 + ks * 8 + q * 2 + 1];
  }

  // =========================== Phase 1 =====================================
  // builder blocks: clear LDS mask array (4 x uint4 per thread = 32 KB)
  if (blockIdx.x < 2) {
    uint4 z4 = {0u, 0u, 0u, 0u};
#pragma unroll
    for (int z = 0; z < 4; z++) ((uint4*)mlds)[t * 4 + z] = z4;
  }

  if (t < 256) {
    // k1: stage W1,W2 (fp32 -> bf16 LDS), 64 rows x 16 float4 granules
#pragma unroll
    for (int z = 0; z < 4; z++) {
      int gi = z * 256 + t;
      int r = gi >> 4, c = gi & 15;
      float4 v1 = ((const float4*)W1)[r * 16 + c];
      float4 v2 = ((const float4*)W2)[r * 16 + c];
      short4 s1, s2;
      s1.x = f2bf(v1.x); s1.y = f2bf(v1.y); s1.z = f2bf(v1.z); s1.w = f2bf(v1.w);
      s2.x = f2bf(v2.x); s2.y = f2bf(v2.y); s2.z = f2bf(v2.z); s2.w = f2bf(v2.w);
      *(short4*)(k1W1s + r * 72 + c * 4) = s1;
      *(short4*)(k1W2s + r * 72 + c * 4) = s2;
    }
  } else if (t < 352) {
    // W_mlp conversion: 24576 granules over 256 blocks = 96/block
    int t4 = blockIdx.x * 96 + (t - 256);  // 0..24575
    if (t4 < 16384) {
      float4 v = ((const float4*)Wm1)[t4];
      short4 s;
      s.x = f2bf(v.x); s.y = f2bf(v.y); s.z = f2bf(v.z); s.w = f2bf(v.w);
      ((short4*)W1B)[t4] = s;
    } else {
      int i2 = t4 - 16384;
      float4 v = ((const float4*)Wm2)[i2];
      short4 s;
      s.x = f2bf(v.x); s.y = f2bf(v.y); s.z = f2bf(v.z); s.w = f2bf(v.w);
      ((short4*)W2B)[i2] = s;
    }
  }

  // eid scatter for this block's 64 edges (plain stores; masks via builders)
  if (t < 64) {
    int e = blockIdx.x * 64 + t;
    eid[ei[e] * NN + ei[NE + e]] = e;
  }

  __syncthreads();  // k1W staged + mlds cleared

  if (t < 256) {
    // k1: C rows -> B-fragments, XY MFMA, bf16 stores
    int be = blockIdx.x * 64 + w * 16;
    short8_t bfrag[2];
#pragma unroll
    for (int ks = 0; ks < 2; ks++) {
      float4 c0 = ((const float4*)C)[(size_t)(be + col) * 16 + ks * 8 + q * 2];
      float4 c1 = ((const float4*)C)[(size_t)(be + col) * 16 + ks * 8 + q * 2 + 1];
      short8_t s;
      s[0] = (short)f2bf(c0.x); s[1] = (short)f2bf(c0.y);
      s[2] = (short)f2bf(c0.z); s[3] = (short)f2bf(c0.w);
      s[4] = (short)f2bf(c1.x); s[5] = (short)f2bf(c1.y);
      s[6] = (short)f2bf(c1.z); s[7] = (short)f2bf(c1.w);
      bfrag[ks] = s;
    }
    float4_t xa[4], ya[4];
#pragma unroll
    for (int ft = 0; ft < 4; ft++) {
      xa[ft] = (float4_t){0.f, 0.f, 0.f, 0.f};
      ya[ft] = (float4_t){0.f, 0.f, 0.f, 0.f};
    }
#pragma unroll
    for (int ks = 0; ks < 2; ks++) {
#pragma unroll
      for (int ft = 0; ft < 4; ft++) {
        short8_t a1 = *(const short8_t*)(k1W1s + (ft * 16 + col) * 72 + ks * 32 + q * 8);
        short8_t a2 = *(const short8_t*)(k1W2s + (ft * 16 + col) * 72 + ks * 32 + q * 8);
        xa[ft] = __builtin_amdgcn_mfma_f32_16x16x32_bf16(a1, bfrag[ks], xa[ft], 0, 0, 0);
        ya[ft] = __builtin_amdgcn_mfma_f32_16x16x32_bf16(a2, bfrag[ks], ya[ft], 0, 0, 0);
      }
    }
#pragma unroll
    for (int ft = 0; ft < 4; ft++) {
      short4 sx, sy;
      sx.x = (short)f2bf(xa[ft][0]); sx.y = (short)f2bf(xa[ft][1]);
      sx.z = (short)f2bf(xa[ft][2]); sx.w = (short)f2bf(xa[ft][3]);
      sy.x = (short)f2bf(ya[ft][0]); sy.y = (short)f2bf(ya[ft][1]);
      sy.z = (short)f2bf(ya[ft][2]); sy.w = (short)f2bf(ya[ft][3]);
      *(short4*)(Xb + (size_t)(be + col) * 64 + ft * 16 + q * 4) = sx;
      *(short4*)(Yb + (size_t)(be + col) * 64 + ft * 16 + q * 4) = sy;
    }
  } else if (t >= 384 && blockIdx.x == 0) {
    // build maskO in LDS: out-neighbor bits of each node
    for (int e = t - 384; e < NE; e += 128) {
      int ii = ei[e], kk = ei[NE + e];
      atomicOr(&mlds[ii * 16 + (kk >> 5)], 1u << (kk & 31));
    }
  } else if (t >= 384 && blockIdx.x == 1) {
    // build maskI in LDS: in-neighbor bits of each node
    for (int e = t - 384; e < NE; e += 128) {
      int ii = ei[e], kk = ei[NE + e];
      atomicOr(&mlds[kk * 16 + (ii >> 5)], 1u << (ii & 31));
    }
  }

  // builder blocks: flush LDS masks to global (coalesced, full overwrite ->
  // no global memset needed anywhere)
  if (blockIdx.x < 2) {           // block-uniform condition: barrier legal
    __syncthreads();
    unsigned* dst = (blockIdx.x == 0) ? maskO : maskI;
#pragma unroll
    for (int z = 0; z < 4; z++)
      ((uint4*)dst)[t * 4 + z] = ((const uint4*)mlds)[t * 4 + z];
  }

  // ======================= grid-wide handoff ===============================
  __threadfence();                 // device-scope release (cross-XCD L2)
  cg::this_grid().sync();

  // =========================== Phase 2 =====================================
  STAGE(0);  // it=0 weight staging; latency hidden under phase S

  unsigned mm0 = maskO[i0 * 16 + gl] & maskI[k0 * 16 + gl];
  unsigned mm1 = maskO[i1 * 16 + gl] & maskI[k1 * 16 + gl];

  // ---------------- Phase S: sparse product -------------------------------
  int cnt0, cnt1;
#pragma unroll
  for (int round = 0; round < 2; round++) {
    unsigned mm = round ? mm1 : mm0;
    int le = round ? le1 : le0;
    int mcnt = __popc(mm);
    int incl = mcnt;
#pragma unroll
    for (int d = 1; d < 16; d <<= 1) {
      int y = __shfl(incl, (lane & 48) | ((gl - d) & 15));
      if (gl >= d) incl += y;
    }
    int off = incl - mcnt;
    int cnt = __shfl(incl, (lane & 48) | 15);
    unsigned bits = mm;
    while (bits) {
      int bb = __builtin_ctz(bits);
      bits &= bits - 1;
      if (off < 32) jlbase[le * 32 + off] = (unsigned short)(gl * 32 + bb);
      off++;
    }
    if (cnt > 32) cnt = 32;  // unreachable for this graph; OOB guard
    if (round) cnt1 = cnt; else cnt0 = cnt;
  }

  // joint first batch of both rounds (independent load chains).
  // cnt==0 guard: clamped jl index would hit uninitialized LDS and a
  // poison-garbage eid slot -> force sv=0 (Xb[0]/Yb[0] valid; fmas masked).
  int b = gl & 7;
  float ac0[4] = {0.f, 0.f, 0.f, 0.f}, ac1[4] = {0.f, 0.f, 0.f, 0.f};
  {
    int jj0 = jlbase[le0 * 32 + (b < cnt0 ? b : 0)] & 511;
    int jj1 = jlbase[le1 * 32 + (b < cnt1 ? b : 0)] & 511;
    int sv0 = (cnt0 > 0) ? eid[(gl < 8) ? (i0 * NN + jj0) : (jj0 * NN + k0)] : 0;
    int sv1 = (cnt1 > 0) ? eid[(gl < 8) ? (i1 * NN + jj1) : (jj1 * NN + k1)] : 0;
    short4 xs0[8], ys0[8], xs1[8], ys1[8];
#pragma unroll
    for (int b2 = 0; b2 < 8; b2++) {
      int s1 = __shfl(sv0, (lane & 48) | b2);
      int s2 = __shfl(sv0, (lane & 48) | (8 + b2));
      xs0[b2] = *(const short4*)(Xb + (size_t)s1 * 64 + gl * 4);
      ys0[b2] = *(const short4*)(Yb + (size_t)s2 * 64 + gl * 4);
    }
#pragma unroll
    for (int b2 = 0; b2 < 8; b2++) {
      int s1 = __shfl(sv1, (lane & 48) | b2);
      int s2 = __shfl(sv1, (lane & 48) | (8 + b2));
      xs1[b2] = *(const short4*)(Xb + (size_t)s1 * 64 + gl * 4);
      ys1[b2] = *(const short4*)(Yb + (size_t)s2 * 64 + gl * 4);
    }
#pragma unroll
    for (int b2 = 0; b2 < 8; b2++) if (b2 < cnt0) {
      ac0[0] = fmaf(bf2f((unsigned short)xs0[b2].x), bf2f((unsigned short)ys0[b2].x), ac0[0]);
      ac0[1] = fmaf(bf2f((unsigned short)xs0[b2].y), bf2f((unsigned short)ys0[b2].y), ac0[1]);
      ac0[2] = fmaf(bf2f((unsigned short)xs0[b2].z), bf2f((unsigned short)ys0[b2].z), ac0[2]);
      ac0[3] = fmaf(bf2f((unsigned short)xs0[b2].w), bf2f((unsigned short)ys0[b2].w), ac0[3]);
    }
#pragma unroll
    for (int b2 = 0; b2 < 8; b2++) if (b2 < cnt1) {
      ac1[0] = fmaf(bf2f((unsigned short)xs1[b2].x), bf2f((unsigned short)ys1[b2].x), ac1[0]);
      ac1[1] = fmaf(bf2f((unsigned short)xs1[b2].y), bf2f((unsigned short)ys1[b2].y), ac1[1]);
      ac1[2] = fmaf(bf2f((unsigned short)xs1[b2].z), bf2f((unsigned short)ys1[b2].z), ac1[2]);
      ac1[3] = fmaf(bf2f((unsigned short)xs1[b2].w), bf2f((unsigned short)ys1[b2].w), ac1[3]);
    }
  }
  // rare tails (cnt > 8): serial batches (cnt >= 9 here, indices valid)
  for (int base = 8; base < cnt0; base += 8) REMBATCH(le0, i0, k0, cnt0, ac0);
  for (int base = 8; base < cnt1; base += 8) REMBATCH(le1, i1, k1, cnt1, ac1);

  {
    short4 o0, o1;
    o0.x = (short)f2bf(ac0[0]); o0.y = (short)f2bf(ac0[1]);
    o0.z = (short)f2bf(ac0[2]); o0.w = (short)f2bf(ac0[3]);
    o1.x = (short)f2bf(ac1[0]); o1.y = (short)f2bf(ac1[1]);
    o1.z = (short)f2bf(ac1[2]); o1.w = (short)f2bf(ac1[3]);
    *(short4*)(tm + le0 * 72 + gl * 4) = o0;
    *(short4*)(tm + le1 * 72 + gl * 4) = o1;
  }

  __syncthreads();  // tm + STAGE(0) visible; jl dead from here on

  // ---------------- Phase M: MLP ------------------------------------------
  short8_t btmp[4];
#pragma unroll
  for (int ks = 0; ks < 2; ks++) {
    float4 c0 = craw[2 * ks], c1 = craw[2 * ks + 1];
    short8_t s;
    s[0] = (short)f2bf(c0.x); s[1] = (short)f2bf(c0.y);
    s[2] = (short)f2bf(c0.z); s[3] = (short)f2bf(c0.w);
    s[4] = (short)f2bf(c1.x); s[5] = (short)f2bf(c1.y);
    s[6] = (short)f2bf(c1.z); s[7] = (short)f2bf(c1.w);
    btmp[ks] = s;
  }
#pragma unroll
  for (int ks = 2; ks < 4; ks++)
    btmp[ks] = *(const short8_t*)(tm + lem * 72 + (ks - 2) * 32 + q * 8);

  float4_t oacc[4];
#pragma unroll
  for (int ft = 0; ft < 4; ft++) oacc[ft] = (float4_t){0.f, 0.f, 0.f, 0.f};

  for (int it = 0; it < 4; it++) {
    // GEMM1: hT[hid][edge] for this half's 64-hid chunk
#pragma unroll
    for (int ht = 0; ht < 4; ht++) {
      float4_t hacc = (float4_t){0.f, 0.f, 0.f, 0.f};
#pragma unroll
      for (int ks = 0; ks < 4; ks++) {
        short8_t af = *(const short8_t*)(W1s + (h * 64 + ht * 16 + col) * 136 + ks * 32 + q * 8);
        hacc = __builtin_amdgcn_mfma_f32_16x16x32_bf16(af, btmp[ks], hacc, 0, 0, 0);
      }
      short4 hp;
      hp.x = (short)f2bf(fmaxf(hacc[0], 0.f));
      hp.y = (short)f2bf(fmaxf(hacc[1], 0.f));
      hp.z = (short)f2bf(fmaxf(hacc[2], 0.f));
      hp.w = (short)f2bf(fmaxf(hacc[3], 0.f));
      *(short4*)(&hS[w][col * 72 + ht * 16 + q * 4]) = hp;
    }
    // hS tile is per-wave: lgkmcnt-only hazard, no block barrier needed

    // GEMM2: oacc += relu(h) @ W2^T over this half's chunk
#pragma unroll
    for (int ks2 = 0; ks2 < 2; ks2++) {
      short8_t a2 = *(const short8_t*)(&hS[w][col * 72 + ks2 * 32 + q * 8]);
#pragma unroll
      for (int ft = 0; ft < 4; ft++) {
        short8_t b2 = *(const short8_t*)(W2s + (ft * 16 + col) * 136 + h * 64 + ks2 * 32 + q * 8);
        oacc[ft] = __builtin_amdgcn_mfma_f32_16x16x32_bf16(a2, b2, oacc[ft], 0, 0, 0);
      }
    }

    if (it < 3) {
      __syncthreads();        // GEMM reads of W1s/W2s done
      STAGE(it + 1);
      __syncthreads();        // staging visible
    }
  }

  __syncthreads();
  float* red = (float*)W1s;  // [64 edges][stride 66] fp32 (16896 B < 34816)
  if (h == 1) {
#pragma unroll
    for (int ft = 0; ft < 4; ft++)
#pragma unroll
      for (int r = 0; r < 4; r++)
        red[(u * 32 + g * 16 + q * 4 + r) * 66 + ft * 16 + col] = oacc[ft][r];
  }
  __syncthreads();
  if (h == 0) {
#pragma unroll
    for (int ft = 0; ft < 4; ft++)
#pragma unroll
      for (int r = 0; r < 4; r++) {
        float v = oacc[ft][r] + red[(u * 32 + g * 16 + q * 4 + r) * 66 + ft * 16 + col];
        out[(size_t)(base_e + q * 4 + r) * 64 + ft * 16 + col] = v;
      }
  }
}

// ---------------------------------------------------------------------------
extern "C" void kernel_launch(void* const* d_in, const int* in_sizes, int n_in,
                              void* d_out, int out_size, void* d_ws, size_t ws_size,
                              hipStream_t stream) {
  const int* ei = (const int*)d_in[0];       // [2, E]
  const float* C = (const float*)d_in[1];    // [E, 64]
  const float* W1 = (const float*)d_in[3];   // [64, 64]
  const float* W2 = (const float*)d_in[4];   // [64, 64]
  const float* Wm1 = (const float*)d_in[5];  // [512, 128]
  const float* Wm2 = (const float*)d_in[6];  // [64, 512]
  float* out = (float*)d_out;                // [E, 64]

  char* p = (char*)d_ws;
  int* eid = (int*)p;                 p += (size_t)NN * NN * 4;
  unsigned* masks = (unsigned*)p;     p += (size_t)16384 * 4;  // maskO|maskI
  unsigned short* Xb = (unsigned short*)p;    p += (size_t)NE * NF * 2;
  unsigned short* Yb = (unsigned short*)p;    p += (size_t)NE * NF * 2;
  unsigned short* W1B = (unsigned short*)p;   p += (size_t)512 * 128 * 2;
  unsigned short* W2B = (unsigned short*)p;   p += (size_t)64 * 512 * 2;
  unsigned* maskO = masks;
  unsigned* maskI = masks + 8192;

  void* args[] = {(void*)&ei, (void*)&C, (void*)&W1, (void*)&W2,
                  (void*)&Wm1, (void*)&Wm2, (void*)&eid, (void*)&maskO,
                  (void*)&maskI, (void*)&Xb, (void*)&Yb, (void*)&W1B,
                  (void*)&W2B, (void*)&out};
  hipLaunchCooperativeKernel((const void*)k_mega, dim3(256), dim3(512),
                             args, 0, stream);
}

// Round 6
// 88.305 us; speedup vs baseline: 2.4726x; 2.4726x over previous
//
#include <hip/hip_runtime.h>

#define NN 512
#define NE 16384
#define NF 64

typedef __attribute__((ext_vector_type(8))) short short8_t;
typedef __attribute__((ext_vector_type(4))) float float4_t;

__device__ inline unsigned short f2bf(float f) {
  unsigned u = __builtin_bit_cast(unsigned, f);
  u += 0x7fff + ((u >> 16) & 1);  // round-to-nearest-even (finite inputs)
  return (unsigned short)(u >> 16);
}
__device__ inline float bf2f(unsigned short u) {
  unsigned v = ((unsigned)u) << 16;
  return __builtin_bit_cast(float, v);
}

// ---------------------------------------------------------------------------
// K1 (R6): X = C@W_L1^T, Y = C@W_L2^T via bf16 MFMA, X/Y split across wave
// pairs: even wave computes X, odd computes Y for the SAME 16 edges.
// Grid 512 x 256thr -> 2 blocks/CU -> 2 waves/SIMD (was 1: every latency
// exposed). C loads hoisted above W staging. Fused: eid scatter (32/block),
// mask atomicOr, W_mlp fp32->bf16 conversion (48 granules/block).
// Numerics identical to R4 (same MFMA ops, same rounding).
// ---------------------------------------------------------------------------
__global__ __launch_bounds__(256) void k_xy_mfma(const float* __restrict__ C,
                                                 const float* __restrict__ W1,
                                                 const float* __restrict__ W2,
                                                 const int* __restrict__ ei,
                                                 const float* __restrict__ Wm1,
                                                 const float* __restrict__ Wm2,
                                                 int* __restrict__ eid,
                                                 unsigned* __restrict__ maskO,
                                                 unsigned* __restrict__ maskI,
                                                 unsigned short* __restrict__ Xb,
                                                 unsigned short* __restrict__ Yb,
                                                 unsigned short* __restrict__ W1B,
                                                 unsigned short* __restrict__ W2B) {
  __shared__ __attribute__((aligned(16))) short W1s[64 * 72];
  __shared__ __attribute__((aligned(16))) short W2s[64 * 72];
  int t = threadIdx.x;
  int w = t >> 6;
  int lane = t & 63;
  int col = lane & 15;
  int q = lane >> 4;
  int p = w >> 1;      // edge-pair group (2 groups of 16 edges per block)
  int xy = w & 1;      // 0 -> X (W1), 1 -> Y (W2)
  int base_e = blockIdx.x * 32 + p * 16;

  // hoisted C row loads (latency hides under W staging below)
  float4 c0[2], c1[2];
#pragma unroll
  for (int ks = 0; ks < 2; ks++) {
    c0[ks] = ((const float4*)C)[(size_t)(base_e + col) * 16 + ks * 8 + q * 2];
    c1[ks] = ((const float4*)C)[(size_t)(base_e + col) * 16 + ks * 8 + q * 2 + 1];
  }

  // scatter this block's 32 edges: id table + presence bits
  if (t < 32) {
    int e = blockIdx.x * 32 + t;
    int i = ei[e];
    int k = ei[NE + e];
    eid[i * NN + k] = e;
    atomicOr(&maskO[i * 16 + (k >> 5)], 1u << (k & 31));
    atomicOr(&maskI[k * 16 + (i >> 5)], 1u << (i & 31));
  }

  // W_mlp conversion side-job: 24576 granules over 512 blocks = 48/block
  if (t >= 64 && t < 112) {
    int t4 = blockIdx.x * 48 + (t - 64);  // 0..24575
    if (t4 < 16384) {
      float4 v = ((const float4*)Wm1)[t4];
      short4 s;
      s.x = f2bf(v.x); s.y = f2bf(v.y); s.z = f2bf(v.z); s.w = f2bf(v.w);
      ((short4*)W1B)[t4] = s;
    } else {
      int i2 = t4 - 16384;
      float4 v = ((const float4*)Wm2)[i2];
      short4 s;
      s.x = f2bf(v.x); s.y = f2bf(v.y); s.z = f2bf(v.z); s.w = f2bf(v.w);
      ((short4*)W2B)[i2] = s;
    }
  }

  // stage W1,W2 (fp32 global -> bf16 LDS), 64 rows x 16 float4 granules
#pragma unroll
  for (int z = 0; z < 4; z++) {
    int gi = z * 256 + t;
    int r = gi >> 4, c = gi & 15;
    float4 v1 = ((const float4*)W1)[r * 16 + c];
    float4 v2 = ((const float4*)W2)[r * 16 + c];
    short4 s1, s2;
    s1.x = f2bf(v1.x); s1.y = f2bf(v1.y); s1.z = f2bf(v1.z); s1.w = f2bf(v1.w);
    s2.x = f2bf(v2.x); s2.y = f2bf(v2.y); s2.z = f2bf(v2.z); s2.w = f2bf(v2.w);
    *(short4*)(W1s + r * 72 + c * 4) = s1;
    *(short4*)(W2s + r * 72 + c * 4) = s2;
  }
  __syncthreads();

  // convert C rows to B-fragments
  short8_t bfrag[2];
#pragma unroll
  for (int ks = 0; ks < 2; ks++) {
    short8_t s;
    s[0] = (short)f2bf(c0[ks].x); s[1] = (short)f2bf(c0[ks].y);
    s[2] = (short)f2bf(c0[ks].z); s[3] = (short)f2bf(c0[ks].w);
    s[4] = (short)f2bf(c1[ks].x); s[5] = (short)f2bf(c1[ks].y);
    s[6] = (short)f2bf(c1[ks].z); s[7] = (short)f2bf(c1[ks].w);
    bfrag[ks] = s;
  }

  const short* Ws = xy ? W2s : W1s;
  unsigned short* Ob = xy ? Yb : Xb;
  float4_t acc[4];
#pragma unroll
  for (int ft = 0; ft < 4; ft++) acc[ft] = (float4_t){0.f, 0.f, 0.f, 0.f};
#pragma unroll
  for (int ks = 0; ks < 2; ks++) {
#pragma unroll
    for (int ft = 0; ft < 4; ft++) {
      short8_t a = *(const short8_t*)(Ws + (ft * 16 + col) * 72 + ks * 32 + q * 8);
      acc[ft] = __builtin_amdgcn_mfma_f32_16x16x32_bf16(a, bfrag[ks], acc[ft], 0, 0, 0);
    }
  }
  // D[row=q*4+r -> f][col -> edge]; store bf16 short4
#pragma unroll
  for (int ft = 0; ft < 4; ft++) {
    short4 so;
    so.x = (short)f2bf(acc[ft][0]); so.y = (short)f2bf(acc[ft][1]);
    so.z = (short)f2bf(acc[ft][2]); so.w = (short)f2bf(acc[ft][3]);
    *(short4*)(Ob + (size_t)(base_e + col) * 64 + ft * 16 + q * 4) = so;
  }
}

// ---------------------------------------------------------------------------
// K2 (fused spmm+mlp), R6 = R4 + double-buffered weight staging (T14 async
// split: issue it+1's global loads to regs BEFORE the GEMMs, ds-write after
// -> staging latency hides under MFMA; barriers 7 -> 4). LDS 132 KB, still
// 1 block/CU (grid 256). Phase S unchanged from R4.
// ---------------------------------------------------------------------------
#define STAGE_LOAD(it, r1, r2) { \
    const uint4* s1g = (const uint4*)W1B; \
    _Pragma("unroll") for (int z = 0; z < 4; z++) { \
      int gi = z * 512 + t; int r = gi >> 4, c = gi & 15; \
      int grow = ((r >> 6) * 4 + (it)) * 64 + (r & 63); \
      r1[z] = s1g[(size_t)grow * 16 + c]; } \
    const uint4* s2g = (const uint4*)W2B; \
    _Pragma("unroll") for (int z = 0; z < 2; z++) { \
      int gi = z * 512 + t; int r = gi >> 4, c = gi & 15; \
      int gc = ((c >> 3) * 4 + (it)) * 8 + (c & 7); \
      r2[z] = s2g[(size_t)r * 64 + gc]; } }

#define STAGE_WRITE(buf, r1, r2) { \
    uint4* d1 = (uint4*)(W1s[(buf)]); \
    _Pragma("unroll") for (int z = 0; z < 4; z++) { \
      int gi = z * 512 + t; int r = gi >> 4, c = gi & 15; \
      d1[r * 17 + c] = r1[z]; } \
    uint4* d2 = (uint4*)(W2s[(buf)]); \
    _Pragma("unroll") for (int z = 0; z < 2; z++) { \
      int gi = z * 512 + t; int r = gi >> 4, c = gi & 15; \
      d2[r * 17 + c] = r2[z]; } }

#define REMBATCH(le, ii, kk, cnt, ac) { \
    int t2 = base + b; \
    int jj = jlbase[(le) * 32 + (t2 < (cnt) ? t2 : base)] & 511; \
    int sv = eid[(gl < 8) ? ((ii) * NN + jj) : (jj * NN + (kk))]; \
    short4 xs[8], ys[8]; \
    _Pragma("unroll") for (int b2 = 0; b2 < 8; b2++) { \
      int s1 = __shfl(sv, (lane & 48) | b2); \
      int s2 = __shfl(sv, (lane & 48) | (8 + b2)); \
      xs[b2] = *(const short4*)(Xb + (size_t)s1 * 64 + gl * 4); \
      ys[b2] = *(const short4*)(Yb + (size_t)s2 * 64 + gl * 4); } \
    _Pragma("unroll") for (int b2 = 0; b2 < 8; b2++) if (base + b2 < (cnt)) { \
      ac[0] = fmaf(bf2f((unsigned short)xs[b2].x), bf2f((unsigned short)ys[b2].x), ac[0]); \
      ac[1] = fmaf(bf2f((unsigned short)xs[b2].y), bf2f((unsigned short)ys[b2].y), ac[1]); \
      ac[2] = fmaf(bf2f((unsigned short)xs[b2].z), bf2f((unsigned short)ys[b2].z), ac[2]); \
      ac[3] = fmaf(bf2f((unsigned short)xs[b2].w), bf2f((unsigned short)ys[b2].w), ac[3]); } }

__global__ __launch_bounds__(512) void k_spmlp(
    const int* __restrict__ ei,
    const int* __restrict__ eid,
    const unsigned* __restrict__ maskO,
    const unsigned* __restrict__ maskI,
    const unsigned short* __restrict__ Xb,
    const unsigned short* __restrict__ Yb,
    const float* __restrict__ C,              // [NE][64] fp32
    const unsigned short* __restrict__ W1B,   // [512][128] bf16
    const unsigned short* __restrict__ W2B,   // [64][512] bf16
    float* __restrict__ out) {                // [NE][64]
  __shared__ __attribute__((aligned(16))) short W1s[2][128 * 136];  // 69632 B
  __shared__ __attribute__((aligned(16))) short W2s[2][64 * 136];   // 34816 B
  __shared__ __attribute__((aligned(16))) short hS[8][16 * 72];     // 18432 B (+jl overlay)
  __shared__ __attribute__((aligned(16))) short tm[64 * 72];        //  9216 B
  // total 132096 B -> 1 block/CU (grid == 256 == #CUs)

  int t = threadIdx.x;
  int w = t >> 6;
  int lane = t & 63;
  int gl = lane & 15;   // lane-in-group
  int grp = lane >> 4;  // group-in-wave
  unsigned short* jlbase = (unsigned short*)hS;  // [64][32], phase-S only

  // ----- phase-M indices (needed for the hoisted C loads) -----
  int u = w >> 2;
  int wl = w & 3;
  int g = wl & 1;
  int h = wl >> 1;
  int col = lane & 15;
  int q = lane >> 4;
  int base_e = blockIdx.x * 64 + u * 32 + g * 16;
  int lem = u * 32 + g * 16 + col;

  // ----- issue phase-S critical loads first -----
  int le0 = w * 4 + grp;
  int le1 = 32 + w * 4 + grp;
  int e0 = blockIdx.x * 64 + le0;
  int e1 = blockIdx.x * 64 + le1;
  int i0 = ei[e0], k0 = ei[NE + e0];
  int i1 = ei[e1], k1 = ei[NE + e1];

  // ----- hoisted independent loads: C rows (fp32) + it=0 weight stage -----
  float4 craw[4];
#pragma unroll
  for (int ks = 0; ks < 2; ks++) {
    craw[2 * ks]     = ((const float4*)C)[(size_t)(base_e + col) * 16 + ks * 8 + q * 2];
    craw[2 * ks + 1] = ((const float4*)C)[(size_t)(base_e + col) * 16 + ks * 8 + q * 2 + 1];
  }
  uint4 sr1[4], sr2[2];
  STAGE_LOAD(0, sr1, sr2);

  unsigned mm0 = maskO[i0 * 16 + gl] & maskI[k0 * 16 + gl];
  unsigned mm1 = maskO[i1 * 16 + gl] & maskI[k1 * 16 + gl];
  STAGE_WRITE(0, sr1, sr2);

  // ---------------- Phase S: sparse product -------------------------------
  int cnt0, cnt1;
#pragma unroll
  for (int round = 0; round < 2; round++) {
    unsigned mm = round ? mm1 : mm0;
    int le = round ? le1 : le0;
    int mcnt = __popc(mm);
    int incl = mcnt;
#pragma unroll
    for (int d = 1; d < 16; d <<= 1) {
      int y = __shfl(incl, (lane & 48) | ((gl - d) & 15));
      if (gl >= d) incl += y;
    }
    int off = incl - mcnt;
    int cnt = __shfl(incl, (lane & 48) | 15);
    unsigned bits = mm;
    while (bits) {
      int bb = __builtin_ctz(bits);
      bits &= bits - 1;
      if (off < 32) jlbase[le * 32 + off] = (unsigned short)(gl * 32 + bb);
      off++;
    }
    if (cnt > 32) cnt = 32;  // unreachable for this graph; OOB guard
    if (round) cnt1 = cnt; else cnt0 = cnt;
  }

  // joint first batch of both rounds (independent load chains).
  // cnt==0 guard: clamped jl index would hit uninitialized LDS and a
  // poison-garbage eid slot -> force sv=0 (Xb[0]/Yb[0] valid; fmas masked).
  int b = gl & 7;
  float ac0[4] = {0.f, 0.f, 0.f, 0.f}, ac1[4] = {0.f, 0.f, 0.f, 0.f};
  {
    int jj0 = jlbase[le0 * 32 + (b < cnt0 ? b : 0)] & 511;
    int jj1 = jlbase[le1 * 32 + (b < cnt1 ? b : 0)] & 511;
    int sv0 = (cnt0 > 0) ? eid[(gl < 8) ? (i0 * NN + jj0) : (jj0 * NN + k0)] : 0;
    int sv1 = (cnt1 > 0) ? eid[(gl < 8) ? (i1 * NN + jj1) : (jj1 * NN + k1)] : 0;
    short4 xs0[8], ys0[8], xs1[8], ys1[8];
#pragma unroll
    for (int b2 = 0; b2 < 8; b2++) {
      int s1 = __shfl(sv0, (lane & 48) | b2);
      int s2 = __shfl(sv0, (lane & 48) | (8 + b2));
      xs0[b2] = *(const short4*)(Xb + (size_t)s1 * 64 + gl * 4);
      ys0[b2] = *(const short4*)(Yb + (size_t)s2 * 64 + gl * 4);
    }
#pragma unroll
    for (int b2 = 0; b2 < 8; b2++) {
      int s1 = __shfl(sv1, (lane & 48) | b2);
      int s2 = __shfl(sv1, (lane & 48) | (8 + b2));
      xs1[b2] = *(const short4*)(Xb + (size_t)s1 * 64 + gl * 4);
      ys1[b2] = *(const short4*)(Yb + (size_t)s2 * 64 + gl * 4);
    }
#pragma unroll
    for (int b2 = 0; b2 < 8; b2++) if (b2 < cnt0) {
      ac0[0] = fmaf(bf2f((unsigned short)xs0[b2].x), bf2f((unsigned short)ys0[b2].x), ac0[0]);
      ac0[1] = fmaf(bf2f((unsigned short)xs0[b2].y), bf2f((unsigned short)ys0[b2].y), ac0[1]);
      ac0[2] = fmaf(bf2f((unsigned short)xs0[b2].z), bf2f((unsigned short)ys0[b2].z), ac0[2]);
      ac0[3] = fmaf(bf2f((unsigned short)xs0[b2].w), bf2f((unsigned short)ys0[b2].w), ac0[3]);
    }
#pragma unroll
    for (int b2 = 0; b2 < 8; b2++) if (b2 < cnt1) {
      ac1[0] = fmaf(bf2f((unsigned short)xs1[b2].x), bf2f((unsigned short)ys1[b2].x), ac1[0]);
      ac1[1] = fmaf(bf2f((unsigned short)xs1[b2].y), bf2f((unsigned short)ys1[b2].y), ac1[1]);
      ac1[2] = fmaf(bf2f((unsigned short)xs1[b2].z), bf2f((unsigned short)ys1[b2].z), ac1[2]);
      ac1[3] = fmaf(bf2f((unsigned short)xs1[b2].w), bf2f((unsigned short)ys1[b2].w), ac1[3]);
    }
  }
  // rare tails (cnt > 8): serial batches (cnt >= 9 here, indices valid)
  for (int base = 8; base < cnt0; base += 8) REMBATCH(le0, i0, k0, cnt0, ac0);
  for (int base = 8; base < cnt1; base += 8) REMBATCH(le1, i1, k1, cnt1, ac1);

  {
    short4 o0, o1;
    o0.x = (short)f2bf(ac0[0]); o0.y = (short)f2bf(ac0[1]);
    o0.z = (short)f2bf(ac0[2]); o0.w = (short)f2bf(ac0[3]);
    o1.x = (short)f2bf(ac1[0]); o1.y = (short)f2bf(ac1[1]);
    o1.z = (short)f2bf(ac1[2]); o1.w = (short)f2bf(ac1[3]);
    *(short4*)(tm + le0 * 72 + gl * 4) = o0;
    *(short4*)(tm + le1 * 72 + gl * 4) = o1;
  }

  __syncthreads();  // tm + STAGE(0) visible; jl dead from here on

  // ---------------- Phase M: MLP ------------------------------------------
  short8_t btmp[4];
#pragma unroll
  for (int ks = 0; ks < 2; ks++) {
    float4 f0 = craw[2 * ks], f1 = craw[2 * ks + 1];
    short8_t s;
    s[0] = (short)f2bf(f0.x); s[1] = (short)f2bf(f0.y);
    s[2] = (short)f2bf(f0.z); s[3] = (short)f2bf(f0.w);
    s[4] = (short)f2bf(f1.x); s[5] = (short)f2bf(f1.y);
    s[6] = (short)f2bf(f1.z); s[7] = (short)f2bf(f1.w);
    btmp[ks] = s;
  }
#pragma unroll
  for (int ks = 2; ks < 4; ks++)
    btmp[ks] = *(const short8_t*)(tm + lem * 72 + (ks - 2) * 32 + q * 8);

  float4_t oacc[4];
#pragma unroll
  for (int ft = 0; ft < 4; ft++) oacc[ft] = (float4_t){0.f, 0.f, 0.f, 0.f};

  for (int it = 0; it < 4; it++) {
    // T14 async split: issue next chunk's global loads before the GEMMs
    if (it < 3) STAGE_LOAD(it + 1, sr1, sr2);
    const short* W1c = W1s[it & 1];
    const short* W2c = W2s[it & 1];

    // GEMM1: hT[hid][edge] for this half's 64-hid chunk
#pragma unroll
    for (int ht = 0; ht < 4; ht++) {
      float4_t hacc = (float4_t){0.f, 0.f, 0.f, 0.f};
#pragma unroll
      for (int ks = 0; ks < 4; ks++) {
        short8_t af = *(const short8_t*)(W1c + (h * 64 + ht * 16 + col) * 136 + ks * 32 + q * 8);
        hacc = __builtin_amdgcn_mfma_f32_16x16x32_bf16(af, btmp[ks], hacc, 0, 0, 0);
      }
      short4 hp;
      hp.x = (short)f2bf(fmaxf(hacc[0], 0.f));
      hp.y = (short)f2bf(fmaxf(hacc[1], 0.f));
      hp.z = (short)f2bf(fmaxf(hacc[2], 0.f));
      hp.w = (short)f2bf(fmaxf(hacc[3], 0.f));
      *(short4*)(&hS[w][col * 72 + ht * 16 + q * 4]) = hp;
    }
    // hS tile is per-wave: lgkmcnt-only hazard, no block barrier needed

    // GEMM2: oacc += relu(h) @ W2^T over this half's chunk
#pragma unroll
    for (int ks2 = 0; ks2 < 2; ks2++) {
      short8_t a2 = *(const short8_t*)(&hS[w][col * 72 + ks2 * 32 + q * 8]);
#pragma unroll
      for (int ft = 0; ft < 4; ft++) {
        short8_t b2 = *(const short8_t*)(W2c + (ft * 16 + col) * 136 + h * 64 + ks2 * 32 + q * 8);
        oacc[ft] = __builtin_amdgcn_mfma_f32_16x16x32_bf16(a2, b2, oacc[ft], 0, 0, 0);
      }
    }

    // write next chunk into the OTHER buffer; one barrier per iteration
    if (it < 3) STAGE_WRITE((it + 1) & 1, sr1, sr2);
    __syncthreads();
  }

  float* red = (float*)W1s;  // [64 edges][stride 66] fp32 (16896 B, buf 0)
  if (h == 1) {
#pragma unroll
    for (int ft = 0; ft < 4; ft++)
#pragma unroll
      for (int r = 0; r < 4; r++)
        red[(u * 32 + g * 16 + q * 4 + r) * 66 + ft * 16 + col] = oacc[ft][r];
  }
  __syncthreads();
  if (h == 0) {
#pragma unroll
    for (int ft = 0; ft < 4; ft++)
#pragma unroll
      for (int r = 0; r < 4; r++) {
        float v = oacc[ft][r] + red[(u * 32 + g * 16 + q * 4 + r) * 66 + ft * 16 + col];
        out[(size_t)(base_e + q * 4 + r) * 64 + ft * 16 + col] = v;
      }
  }
}

// ---------------------------------------------------------------------------
extern "C" void kernel_launch(void* const* d_in, const int* in_sizes, int n_in,
                              void* d_out, int out_size, void* d_ws, size_t ws_size,
                              hipStream_t stream) {
  const int* ei = (const int*)d_in[0];       // [2, E]
  const float* C = (const float*)d_in[1];    // [E, 64]
  const float* W1 = (const float*)d_in[3];   // [64, 64]
  const float* W2 = (const float*)d_in[4];   // [64, 64]
  const float* Wm1 = (const float*)d_in[5];  // [512, 128]
  const float* Wm2 = (const float*)d_in[6];  // [64, 512]
  float* out = (float*)d_out;                // [E, 64]

  char* p = (char*)d_ws;
  int* eid = (int*)p;                 p += (size_t)NN * NN * 4;
  unsigned* masks = (unsigned*)p;     p += (size_t)16384 * 4;  // maskO|maskI
  unsigned short* Xb = (unsigned short*)p;    p += (size_t)NE * NF * 2;
  unsigned short* Yb = (unsigned short*)p;    p += (size_t)NE * NF * 2;
  unsigned short* W1B = (unsigned short*)p;   p += (size_t)512 * 128 * 2;
  unsigned short* W2B = (unsigned short*)p;   p += (size_t)64 * 512 * 2;
  unsigned* maskO = masks;
  unsigned* maskI = masks + 8192;

  hipMemsetAsync(masks, 0, 16384 * sizeof(unsigned), stream);
  k_xy_mfma<<<NE / 32, 256, 0, stream>>>(C, W1, W2, ei, Wm1, Wm2, eid,
                                         maskO, maskI, Xb, Yb, W1B, W2B);
  k_spmlp<<<NE / 64, 512, 0, stream>>>(ei, eid, maskO, maskI, Xb, Yb,
                                       C, W1B, W2B, out);
}